// Round 6
// baseline (1096.534 us; speedup 1.0000x reference)
//
#include <hip/hip_runtime.h>
#include <hip/hip_cooperative_groups.h>

namespace cg = cooperative_groups;

#define RR 48
#define GG 300
#define HW2 (GG * GG)
#define NPLANE (RR * HW2)
#define NVEC (RR * GG)
#define CC 27
#define NBUCK 32768  // 32^3 Morton buckets
#define TP 64        // points per block tile (37.4 KB LDS -> 4 blocks/CU)
#define TPP 65       // padded LDS column count

// transpose geometry: 16-row x 256-pos tiles, 3 passes over R=48
#define TROWS 16
#define TCOLS 256
#define PCHUNK ((HW2 + TCOLS - 1) / TCOLS)  // 352 chunks (tail = 144 pos)
#define NPASS (RR / TROWS)                  // 3
#define TPB3 (3 * NPASS * PCHUNK)           // 3168 plane-transpose blocks
#define VBLK ((3 * NVEC + 255) / 256)       // 169 vec-transpose blocks
#define TROW2 260                           // LDS row stride (words), 16B-aligned
#define SCANB (NBUCK / 256)                 // 128 scan blocks

struct Axis { int i0, i1; float f; };

__device__ __forceinline__ Axis axis_interp(float x) {
  float g = x * 2.0f - 1.0f;
  float ih = (g + 1.0f) * 0.5f * (float)(GG - 1);
  int i0 = (int)floorf(ih);
  i0 = i0 < 0 ? 0 : (i0 > GG - 1 ? GG - 1 : i0);
  int i1 = i0 + 1 > GG - 1 ? GG - 1 : i0 + 1;
  Axis a; a.i0 = i0; a.i1 = i1; a.f = ih - (float)i0;
  return a;
}

// ---------------- sort machinery ----------------
__device__ __forceinline__ unsigned part3(unsigned v) {
  unsigned r = 0;
  r |= (v & 1u);
  r |= (v & 2u) << 2;
  r |= (v & 4u) << 4;
  r |= (v & 8u) << 6;
  r |= (v & 16u) << 8;
  return r;
}

__device__ __forceinline__ int morton_key(float x, float y, float z) {
  int qx = (int)(x * 32.0f); qx = qx < 0 ? 0 : (qx > 31 ? 31 : qx);
  int qy = (int)(y * 32.0f); qy = qy < 0 ? 0 : (qy > 31 ? 31 : qy);
  int qz = (int)(z * 32.0f); qz = qz < 0 ? 0 : (qz > 31 ? 31 : qz);
  return (int)(part3((unsigned)qx) | (part3((unsigned)qy) << 1) | (part3((unsigned)qz) << 2));
}

// ---------------- transpose bodies (shared by coop + fallback) ----------
__device__ __forceinline__ void plane_transpose_vb(
    int vb, int t, float* __restrict__ tile,
    const float* __restrict__ p0, const float* __restrict__ p1, const float* __restrict__ p2,
    float* __restrict__ t0, float* __restrict__ t1, float* __restrict__ t2) {
  int rem = vb;
  int plane = rem / (NPASS * PCHUNK);
  rem -= plane * (NPASS * PCHUNK);
  int pass = rem / PCHUNK;
  int chunk = rem - pass * PCHUNK;
  const float* in = (plane == 0) ? p0 : (plane == 1) ? p1 : p2;
  float* outp = (plane == 0) ? t0 : (plane == 1) ? t1 : t2;
  int base = chunk * TCOLS;
  int rbase = pass * TROWS;

  int p4 = t & 63;
  int rg = t >> 6;
#pragma unroll
  for (int i = 0; i < TROWS / 4; ++i) {
    int r = i * 4 + rg;
    int pos = base + p4 * 4;
    if (pos < HW2) {
      float4 v = *(const float4*)(in + (size_t)(rbase + r) * HW2 + pos);
      *(float4*)&tile[r * TROW2 + p4 * 4] = v;
    }
  }
  __syncthreads();

  int c4 = t & 3;
  int hwl = t >> 2;
#pragma unroll
  for (int jj = 0; jj < 4; ++jj) {
    int hw = jj * 64 + hwl;
    if (base + hw < HW2) {
      float4 w;
      w.x = tile[(c4 * 4 + 0) * TROW2 + hw];
      w.y = tile[(c4 * 4 + 1) * TROW2 + hw];
      w.z = tile[(c4 * 4 + 2) * TROW2 + hw];
      w.w = tile[(c4 * 4 + 3) * TROW2 + hw];
      *(float4*)(outp + (size_t)(base + hw) * RR + rbase + c4 * 4) = w;
    }
  }
}

__device__ __forceinline__ void vec_transpose_e(
    int e, const float* __restrict__ v0, const float* __restrict__ v1,
    const float* __restrict__ v2, float* __restrict__ tv0,
    float* __restrict__ tv1, float* __restrict__ tv2) {
  if (e < 3 * NVEC) {
    int v = e / NVEC;
    int rem = e - v * NVEC;
    int i = rem / RR;
    int r = rem - i * RR;
    const float* in = (v == 0) ? v0 : (v == 1) ? v1 : v2;
    float* out = (v == 0) ? tv0 : (v == 1) ? tv1 : tv2;
    out[i * RR + r] = in[r * GG + i];
  }
}

// ---------------- cooperative preprocessing: all of it in one kernel ----
// A: transposes || hist -> sync -> B: 3-step parallel scan -> sync -> C: scatter
__global__ void __launch_bounds__(256) preprocess_coop(
    const float* __restrict__ xyz, int n,
    int* __restrict__ offs, int* __restrict__ aux,
    int* __restrict__ sidx, float4* __restrict__ sxyz,
    const float* __restrict__ p0, const float* __restrict__ p1, const float* __restrict__ p2,
    float* __restrict__ t0, float* __restrict__ t1, float* __restrict__ t2,
    const float* __restrict__ v0, const float* __restrict__ v1, const float* __restrict__ v2,
    float* __restrict__ tv0, float* __restrict__ tv1, float* __restrict__ tv2) {
  cg::grid_group grid = cg::this_grid();
  __shared__ float tile[TROWS * TROW2];  // 16.6 KB; aliased as int for scans
  int* itile = (int*)tile;
  int t = threadIdx.x;
  int gtid = blockIdx.x * 256 + t;
  int gsize = gridDim.x * 256;

  // ---- phase A: transposes (heavy, first) || histogram ----
  int nvbA = TPB3 + VBLK + (n + 255) / 256;
  for (int vb = blockIdx.x; vb < nvbA; vb += gridDim.x) {
    __syncthreads();  // tile reuse guard across virtual blocks
    if (vb < TPB3) {
      plane_transpose_vb(vb, t, tile, p0, p1, p2, t0, t1, t2);
    } else if (vb < TPB3 + VBLK) {
      vec_transpose_e((vb - TPB3) * 256 + t, v0, v1, v2, tv0, tv1, tv2);
    } else {
      int i = (vb - TPB3 - VBLK) * 256 + t;
      if (i < n)
        atomicAdd(&offs[morton_key(xyz[i * 3], xyz[i * 3 + 1], xyz[i * 3 + 2])], 1);
    }
  }
  grid.sync();

  // ---- phase B1: 128 blocks each scan 256 buckets ----
  int cnt = 0;
  if (blockIdx.x < SCANB) {
    cnt = offs[gtid];
    itile[t] = cnt;
    __syncthreads();
    for (int off = 1; off < 256; off <<= 1) {
      int u = (t >= off) ? itile[t - off] : 0;
      __syncthreads();
      itile[t] += u;
      __syncthreads();
    }
    offs[gtid] = itile[t] - cnt;              // exclusive within block
    if (t == 255) aux[blockIdx.x] = itile[t]; // block total
  }
  grid.sync();

  // ---- phase B2: block 0 scans the 128 block totals ----
  if (blockIdx.x == 0) {
    int v = (t < SCANB) ? aux[t] : 0;
    itile[t] = v;
    __syncthreads();
    for (int off = 1; off < 256; off <<= 1) {
      int u = (t >= off) ? itile[t - off] : 0;
      __syncthreads();
      itile[t] += u;
      __syncthreads();
    }
    if (t < SCANB) aux[t] = itile[t] - v;     // exclusive block prefix
  }
  grid.sync();

  // ---- phase B3: add block prefixes ----
  if (blockIdx.x < SCANB) offs[gtid] += aux[blockIdx.x];
  grid.sync();

  // ---- phase C: scatter sorted (x,y,z,idx) records ----
  for (int i = gtid; i < n; i += gsize) {
    float x = xyz[i * 3], y = xyz[i * 3 + 1], z = xyz[i * 3 + 2];
    int key = morton_key(x, y, z);
    int pos = atomicAdd(&offs[key], 1);
    if (sxyz) sxyz[pos] = make_float4(x, y, z, __int_as_float(i));
    else      sidx[pos] = i;
  }
}

// ---------------- fallback chain (non-cooperative), round-5 proven ------
__global__ void __launch_bounds__(256) hist_kernel(const float* __restrict__ xyz, int n,
                                                   int* __restrict__ offs) {
  int i = blockIdx.x * blockDim.x + threadIdx.x;
  if (i >= n) return;
  atomicAdd(&offs[morton_key(xyz[i * 3], xyz[i * 3 + 1], xyz[i * 3 + 2])], 1);
}

__global__ void __launch_bounds__(1024) scan_kernel(int* __restrict__ offs) {
  __shared__ int part[1024];
  int t = threadIdx.x;
  int base = t * (NBUCK / 1024);
  int loc[NBUCK / 1024];
  int s = 0;
#pragma unroll
  for (int i = 0; i < NBUCK / 1024; ++i) { loc[i] = offs[base + i]; s += loc[i]; }
  part[t] = s;
  __syncthreads();
  for (int off = 1; off < 1024; off <<= 1) {
    int u = (t >= off) ? part[t - off] : 0;
    __syncthreads();
    part[t] += u;
    __syncthreads();
  }
  int excl = (t == 0) ? 0 : part[t - 1];
#pragma unroll
  for (int i = 0; i < NBUCK / 1024; ++i) {
    int c = loc[i];
    offs[base + i] = excl;
    excl += c;
  }
}

__global__ void __launch_bounds__(256) trans_scatter_kernel(
    const float* __restrict__ xyz, int n, int* __restrict__ offs,
    int* __restrict__ sidx, float4* __restrict__ sxyz, int scb,
    const float* __restrict__ p0, const float* __restrict__ p1, const float* __restrict__ p2,
    float* __restrict__ t0, float* __restrict__ t1, float* __restrict__ t2,
    const float* __restrict__ v0, const float* __restrict__ v1, const float* __restrict__ v2,
    float* __restrict__ tv0, float* __restrict__ tv1, float* __restrict__ tv2) {
  __shared__ float tile[TROWS * TROW2];
  int bb = blockIdx.x;
  int t = threadIdx.x;

  if (bb < scb) {
    int i = bb * 256 + t;
    if (i < n) {
      float x = xyz[i * 3], y = xyz[i * 3 + 1], z = xyz[i * 3 + 2];
      int key = morton_key(x, y, z);
      int pos = atomicAdd(&offs[key], 1);
      if (sxyz) sxyz[pos] = make_float4(x, y, z, __int_as_float(i));
      else      sidx[pos] = i;
    }
  } else if (bb < scb + TPB3) {
    plane_transpose_vb(bb - scb, t, tile, p0, p1, p2, t0, t1, t2);
  } else {
    vec_transpose_e((bb - scb - TPB3) * 256 + t, v0, v1, v2, tv0, tv1, tv2);
  }
}

// ---------------- fused main ----------------
// One corner-run gather + interpolation for one seg; lane l<12 covers channels 4l..4l+3.
__device__ __forceinline__ void gather_seg(const float* __restrict__ P, Axis ai, Axis aj,
                                           const float* __restrict__ V, Axis ak,
                                           int r4, float* __restrict__ dst) {
  float fi = ai.f, fj = aj.f, fk = ak.f;
  float w00 = (1.f - fi) * (1.f - fj);
  float w01 = (1.f - fi) * fj;
  float w10 = fi * (1.f - fj);
  float w11 = fi * fj;
  float omk = 1.f - fk;
  float4 q00 = *(const float4*)(P + (ai.i0 * GG + aj.i0) * RR + r4);
  float4 q01 = *(const float4*)(P + (ai.i0 * GG + aj.i1) * RR + r4);
  float4 q10 = *(const float4*)(P + (ai.i1 * GG + aj.i0) * RR + r4);
  float4 q11 = *(const float4*)(P + (ai.i1 * GG + aj.i1) * RR + r4);
  float4 b0 = *(const float4*)(V + ak.i0 * RR + r4);
  float4 b1 = *(const float4*)(V + ak.i1 * RR + r4);
  float t0 = (w00 * q00.x + w01 * q01.x + w10 * q10.x + w11 * q11.x) * (omk * b0.x + fk * b1.x);
  float t1 = (w00 * q00.y + w01 * q01.y + w10 * q10.y + w11 * q11.y) * (omk * b0.y + fk * b1.y);
  float t2 = (w00 * q00.z + w01 * q01.z + w10 * q10.z + w11 * q11.z) * (omk * b0.z + fk * b1.z);
  float t3 = (w00 * q00.w + w01 * q01.w + w10 * q10.w + w11 * q11.w) * (omk * b0.w + fk * b1.w);
  dst[(r4 + 0) * TPP] = t0;
  dst[(r4 + 1) * TPP] = t1;
  dst[(r4 + 2) * TPP] = t2;
  dst[(r4 + 3) * TPP] = t3;
}

__global__ void __launch_bounds__(256, 4) tensorf_fused(
    const float4* __restrict__ sxyz, const int* __restrict__ sidx,
    const float* __restrict__ xyz,
    const float* __restrict__ Txy, const float* __restrict__ Txz, const float* __restrict__ Tyz,
    const float* __restrict__ Tx, const float* __restrict__ Ty, const float* __restrict__ Tz,
    const float* __restrict__ F, float* __restrict__ out, int n, int chunkLen) {
  __shared__ float featT[144 * TPP];  // 37.4 KB -> 4 blocks/CU
  __shared__ int oiS[TP];
  int b = blockIdx.x;
  int nb = (b & 7) * chunkLen + (b >> 3);  // XCD-aware: each XCD streams one Morton chunk
  int base = nb * TP;
  int tid = threadIdx.x;
  int g = tid >> 4;   // group 0..15, one point per group per iter
  int l = tid & 15;   // lane within group; lanes 0..11 do the loads

  // ---- phase 1: coalesced gather + interpolate -> featT[144][TP] ----
#pragma unroll 1
  for (int it = 0; it < TP / 16; ++it) {
    int pl = (it << 4) + g;
    int sp = base + pl;
    if (sp < n) {
      float x, y, z;
      int oi;
      if (sxyz) {
        float4 p4 = sxyz[sp];  // coalesced sorted records
        x = p4.x; y = p4.y; z = p4.z;
        oi = __float_as_int(p4.w);
      } else {
        oi = sidx[sp];
        x = xyz[oi * 3 + 0];
        y = xyz[oi * 3 + 1];
        z = xyz[oi * 3 + 2];
      }
      if (l == 12) oiS[pl] = oi;
      Axis ax = axis_interp(x), ay = axis_interp(y), az = axis_interp(z);
      if (l < 12) {
        int r4 = l << 2;
        float* dst = &featT[pl];
        gather_seg(Txy, ax, ay, Tz, az, r4, dst + 0 * RR * TPP);
        gather_seg(Txz, ax, az, Ty, ay, r4, dst + 1 * RR * TPP);
        gather_seg(Tyz, ay, az, Tx, ax, r4, dst + 2 * RR * TPP);
      }
    }
  }
  __syncthreads();

  // ---- phase 2: feat[144] @ F[144][27], 4 threads per point ----
  // q = wave index, FORCED uniform via readfirstlane so the F pointer lives in
  // SGPRs and all F reads are s_load broadcasts (round-2 regression: plain
  // tid>>6 made these 1008 per-lane global_load_dword + VGPR address math).
  int p = tid & (TP - 1);
  int q = __builtin_amdgcn_readfirstlane(tid >> 6);  // wave-uniform 0..3
  int cbase = (q == 3) ? 20 : q * 7;  // q3 overlaps q2 at c20 to stay in-bounds
  const float* Fh = F + cbase;

  float acc[7];
#pragma unroll
  for (int c = 0; c < 7; ++c) acc[c] = 0.f;

#pragma unroll 4
  for (int k = 0; k < 144; ++k) {
    float fv = featT[k * TPP + p];
#pragma unroll
    for (int c = 0; c < 7; ++c) acc[c] = fmaf(fv, Fh[k * CC + c], acc[c]);
  }

  int sp = base + p;
  if (sp < n) {
    int oi = oiS[p];
    float* o = out + (size_t)oi * CC + cbase;
    if (q != 3) o[0] = acc[0];  // q3's c==0 (channel 20) is q2's copy
#pragma unroll
    for (int c = 1; c < 7; ++c) o[c] = acc[c];
  }
}

// ---------------- fallback (no workspace) ----------------
__global__ void __launch_bounds__(256) tensorf_naive(
    const float* __restrict__ xyz,
    const float* __restrict__ Pxy, const float* __restrict__ Pxz, const float* __restrict__ Pyz,
    const float* __restrict__ Vx, const float* __restrict__ Vy, const float* __restrict__ Vz,
    const float* __restrict__ F, float* __restrict__ out, int n) {
  int idx = blockIdx.x * blockDim.x + threadIdx.x;
  if (idx >= n) return;
  float x = xyz[idx * 3], y = xyz[idx * 3 + 1], z = xyz[idx * 3 + 2];
  Axis ax = axis_interp(x), ay = axis_interp(y), az = axis_interp(z);
  float acc[CC];
#pragma unroll
  for (int c = 0; c < CC; ++c) acc[c] = 0.f;
  const float* Ps[3] = {Pxy, Pxz, Pyz};
  const float* Vs[3] = {Vz, Vy, Vx};
  Axis A[3][2] = {{ax, ay}, {ax, az}, {ay, az}};
  Axis K[3] = {az, ay, ax};
#pragma unroll 1
  for (int s = 0; s < 3; ++s) {
    Axis ai = A[s][0], aj = A[s][1], ak = K[s];
    float fi = ai.f, fj = aj.f, fk = ak.f;
    float w00 = (1.f - fi) * (1.f - fj), w01 = (1.f - fi) * fj;
    float w10 = fi * (1.f - fj), w11 = fi * fj, omk = 1.f - fk;
#pragma unroll 1
    for (int r = 0; r < RR; ++r) {
      const float* pr = Ps[s] + r * HW2;
      float ft = (w00 * pr[ai.i0 * GG + aj.i0] + w01 * pr[ai.i0 * GG + aj.i1] +
                  w10 * pr[ai.i1 * GG + aj.i0] + w11 * pr[ai.i1 * GG + aj.i1]) *
                 (omk * Vs[s][r * GG + ak.i0] + fk * Vs[s][r * GG + ak.i1]);
      const float* Fr = F + (s * RR + r) * CC;
#pragma unroll
      for (int c = 0; c < CC; ++c) acc[c] = fmaf(ft, Fr[c], acc[c]);
    }
  }
  float* o = out + (size_t)idx * CC;
#pragma unroll
  for (int c = 0; c < CC; ++c) o[c] = acc[c];
}

extern "C" void kernel_launch(void* const* d_in, const int* in_sizes, int n_in,
                              void* d_out, int out_size, void* d_ws, size_t ws_size,
                              hipStream_t stream) {
  const float* xyz = (const float*)d_in[0];
  const float* pxy = (const float*)d_in[1];
  const float* pxz = (const float*)d_in[2];
  const float* pyz = (const float*)d_in[3];
  const float* vx = (const float*)d_in[4];
  const float* vy = (const float*)d_in[5];
  const float* vz = (const float*)d_in[6];
  const float* F = (const float*)d_in[7];
  float* out = (float*)d_out;
  int n = in_sizes[0] / 3;
  int nblk = (n + 255) / 256;

  size_t fixed = (size_t)(3 * NPLANE + 3 * NVEC) * sizeof(float) +
                 (size_t)(NBUCK + 256) * sizeof(int);
  size_t need1 = fixed + (size_t)n * sizeof(int);      // sorted-index variant
  size_t need2 = fixed + (size_t)n * sizeof(float4);   // sorted-record variant

  if (ws_size >= need1) {
    float* w = (float*)d_ws;
    float* Txy = w;
    float* Txz = Txy + NPLANE;
    float* Tyz = Txz + NPLANE;
    float* Tx = Tyz + NPLANE;
    float* Ty = Tx + NVEC;
    float* Tz = Ty + NVEC;
    int* offs = (int*)(Tz + NVEC);
    int* aux = offs + NBUCK;

    int* sidx = nullptr;
    float4* sxyz = nullptr;
    if (ws_size >= need2) sxyz = (float4*)(aux + 256);
    else sidx = aux + 256;

    hipMemsetAsync(offs, 0, (size_t)NBUCK * sizeof(int), stream);

    // cooperative grid size: co-resident blocks for this kernel (cached once)
    static int coopGrid = -1;
    if (coopGrid < 0) {
      int bpc = 0, dev = 0;
      hipDeviceProp_t prop;
      if (hipOccupancyMaxActiveBlocksPerMultiprocessor(&bpc, preprocess_coop, 256, 0) ==
              hipSuccess &&
          bpc > 0 && hipGetDevice(&dev) == hipSuccess &&
          hipGetDeviceProperties(&prop, dev) == hipSuccess) {
        long g = (long)bpc * prop.multiProcessorCount;
        coopGrid = (int)(g > 4096 ? 4096 : g);
      } else {
        coopGrid = 0;
      }
    }

    bool coopOK = false;
    if (coopGrid >= SCANB) {
      void* args[] = {(void*)&xyz, (void*)&n,   (void*)&offs, (void*)&aux,
                      (void*)&sidx, (void*)&sxyz, (void*)&pxy,  (void*)&pxz,
                      (void*)&pyz,  (void*)&Txy,  (void*)&Txz,  (void*)&Tyz,
                      (void*)&vx,   (void*)&vy,   (void*)&vz,   (void*)&Tx,
                      (void*)&Ty,   (void*)&Tz};
      hipError_t e = hipLaunchCooperativeKernel((const void*)preprocess_coop,
                                                dim3(coopGrid), dim3(256), args, 0, stream);
      coopOK = (e == hipSuccess);
    }

    if (!coopOK) {
      // proven round-5 chain: hist -> scan -> [scatter || transposes]
      hist_kernel<<<nblk, 256, 0, stream>>>(xyz, n, offs);
      scan_kernel<<<1, 1024, 0, stream>>>(offs);
      trans_scatter_kernel<<<nblk + TPB3 + VBLK, 256, 0, stream>>>(
          xyz, n, offs, sidx, sxyz, nblk,
          pxy, pxz, pyz, Txy, Txz, Tyz, vx, vy, vz, Tx, Ty, Tz);
    }

    int ntile = (n + TP - 1) / TP;
    int chunkLen = (ntile + 7) / 8;
    tensorf_fused<<<chunkLen * 8, 256, 0, stream>>>(sxyz, sidx, xyz, Txy, Txz, Tyz,
                                                    Tx, Ty, Tz, F, out, n, chunkLen);
  } else {
    tensorf_naive<<<nblk, 256, 0, stream>>>(xyz, pxy, pxz, pyz, vx, vy, vz, F, out, n);
  }
}

// Round 9
// 537.690 us; speedup vs baseline: 2.0393x; 2.0393x over previous
//
#include <hip/hip_runtime.h>

#define RR 48
#define GG 300
#define HW2 (GG * GG)
#define NPLANE (RR * HW2)
#define NVEC (RR * GG)
#define CC 27
#define NBUCK 32768  // 32^3 Morton buckets
#define TP 64        // points per block tile
#define FROW 148     // featT row stride in words: 16B-aligned rows, 37.9 KB total

// transpose geometry: 16-row x 256-pos tiles, 3 passes over R=48
#define TROWS 16
#define TCOLS 256
#define PCHUNK ((HW2 + TCOLS - 1) / TCOLS)  // 352 chunks (tail = 144 pos)
#define NPASS (RR / TROWS)                  // 3
#define TPB3 (3 * NPASS * PCHUNK)           // 3168 plane-transpose blocks
#define VBLK ((3 * NVEC + 255) / 256)       // 169 vec-transpose blocks
#define TROW2 260                           // LDS row stride (words), 16B-aligned

struct Axis { int i0, i1; float f; };

__device__ __forceinline__ Axis axis_interp(float x) {
  float g = x * 2.0f - 1.0f;
  float ih = (g + 1.0f) * 0.5f * (float)(GG - 1);
  int i0 = (int)floorf(ih);
  i0 = i0 < 0 ? 0 : (i0 > GG - 1 ? GG - 1 : i0);
  int i1 = i0 + 1 > GG - 1 ? GG - 1 : i0 + 1;
  Axis a; a.i0 = i0; a.i1 = i1; a.f = ih - (float)i0;
  return a;
}

// ---------------- sort machinery ----------------
__device__ __forceinline__ unsigned part3(unsigned v) {
  unsigned r = 0;
  r |= (v & 1u);
  r |= (v & 2u) << 2;
  r |= (v & 4u) << 4;
  r |= (v & 8u) << 6;
  r |= (v & 16u) << 8;
  return r;
}

__device__ __forceinline__ int morton_key(float x, float y, float z) {
  int qx = (int)(x * 32.0f); qx = qx < 0 ? 0 : (qx > 31 ? 31 : qx);
  int qy = (int)(y * 32.0f); qy = qy < 0 ? 0 : (qy > 31 ? 31 : qy);
  int qz = (int)(z * 32.0f); qz = qz < 0 ? 0 : (qz > 31 ? 31 : qz);
  return (int)(part3((unsigned)qx) | (part3((unsigned)qy) << 1) | (part3((unsigned)qz) << 2));
}

__global__ void __launch_bounds__(256) hist_kernel(const float* __restrict__ xyz, int n,
                                                   int* __restrict__ offs) {
  int i = blockIdx.x * blockDim.x + threadIdx.x;
  if (i >= n) return;
  atomicAdd(&offs[morton_key(xyz[i * 3], xyz[i * 3 + 1], xyz[i * 3 + 2])], 1);
}

__global__ void __launch_bounds__(1024) scan_kernel(int* __restrict__ offs) {
  __shared__ int part[1024];
  int t = threadIdx.x;
  int base = t * (NBUCK / 1024);
  int loc[NBUCK / 1024];
  int s = 0;
#pragma unroll
  for (int i = 0; i < NBUCK / 1024; ++i) { loc[i] = offs[base + i]; s += loc[i]; }
  part[t] = s;
  __syncthreads();
  for (int off = 1; off < 1024; off <<= 1) {
    int u = (t >= off) ? part[t - off] : 0;
    __syncthreads();
    part[t] += u;
    __syncthreads();
  }
  int excl = (t == 0) ? 0 : part[t - 1];
#pragma unroll
  for (int i = 0; i < NBUCK / 1024; ++i) {
    int c = loc[i];
    offs[base + i] = excl;
    excl += c;
  }
}

// ---------------- transpose bodies ----------
__device__ __forceinline__ void plane_transpose_vb(
    int vb, int t, float* __restrict__ tile,
    const float* __restrict__ p0, const float* __restrict__ p1, const float* __restrict__ p2,
    float* __restrict__ t0, float* __restrict__ t1, float* __restrict__ t2) {
  int rem = vb;
  int plane = rem / (NPASS * PCHUNK);
  rem -= plane * (NPASS * PCHUNK);
  int pass = rem / PCHUNK;
  int chunk = rem - pass * PCHUNK;
  const float* in = (plane == 0) ? p0 : (plane == 1) ? p1 : p2;
  float* outp = (plane == 0) ? t0 : (plane == 1) ? t1 : t2;
  int base = chunk * TCOLS;
  int rbase = pass * TROWS;

  int p4 = t & 63;
  int rg = t >> 6;
#pragma unroll
  for (int i = 0; i < TROWS / 4; ++i) {
    int r = i * 4 + rg;
    int pos = base + p4 * 4;
    if (pos < HW2) {
      float4 v = *(const float4*)(in + (size_t)(rbase + r) * HW2 + pos);
      *(float4*)&tile[r * TROW2 + p4 * 4] = v;
    }
  }
  __syncthreads();

  int c4 = t & 3;
  int hwl = t >> 2;
#pragma unroll
  for (int jj = 0; jj < 4; ++jj) {
    int hw = jj * 64 + hwl;
    if (base + hw < HW2) {
      float4 w;
      w.x = tile[(c4 * 4 + 0) * TROW2 + hw];
      w.y = tile[(c4 * 4 + 1) * TROW2 + hw];
      w.z = tile[(c4 * 4 + 2) * TROW2 + hw];
      w.w = tile[(c4 * 4 + 3) * TROW2 + hw];
      *(float4*)(outp + (size_t)(base + hw) * RR + rbase + c4 * 4) = w;
    }
  }
}

__device__ __forceinline__ void vec_transpose_e(
    int e, const float* __restrict__ v0, const float* __restrict__ v1,
    const float* __restrict__ v2, float* __restrict__ tv0,
    float* __restrict__ tv1, float* __restrict__ tv2) {
  if (e < 3 * NVEC) {
    int v = e / NVEC;
    int rem = e - v * NVEC;
    int i = rem / RR;
    int r = rem - i * RR;
    const float* in = (v == 0) ? v0 : (v == 1) ? v1 : v2;
    float* out = (v == 0) ? tv0 : (v == 1) ? tv1 : tv2;
    out[i * RR + r] = in[r * GG + i];
  }
}

// merged: scatter || plane transposes || vec transposes (round-5 proven)
__global__ void __launch_bounds__(256) trans_scatter_kernel(
    const float* __restrict__ xyz, int n, int* __restrict__ offs,
    int* __restrict__ sidx, float4* __restrict__ sxyz, int scb,
    const float* __restrict__ p0, const float* __restrict__ p1, const float* __restrict__ p2,
    float* __restrict__ t0, float* __restrict__ t1, float* __restrict__ t2,
    const float* __restrict__ v0, const float* __restrict__ v1, const float* __restrict__ v2,
    float* __restrict__ tv0, float* __restrict__ tv1, float* __restrict__ tv2) {
  __shared__ float tile[TROWS * TROW2];
  int bb = blockIdx.x;
  int t = threadIdx.x;

  if (bb < scb) {
    int i = bb * 256 + t;
    if (i < n) {
      float x = xyz[i * 3], y = xyz[i * 3 + 1], z = xyz[i * 3 + 2];
      int key = morton_key(x, y, z);
      int pos = atomicAdd(&offs[key], 1);
      if (sxyz) sxyz[pos] = make_float4(x, y, z, __int_as_float(i));
      else      sidx[pos] = i;
    }
  } else if (bb < scb + TPB3) {
    plane_transpose_vb(bb - scb, t, tile, p0, p1, p2, t0, t1, t2);
  } else {
    vec_transpose_e((bb - scb - TPB3) * 256 + t, v0, v1, v2, tv0, tv1, tv2);
  }
}

// ---------------- fused main ----------------
// featT layout: [point][channel] = [TP][FROW] so both LDS sides are b128:
// phase 1 writes one float4 per gather_seg; phase 2 reads float4 along k.
__device__ __forceinline__ void gather_seg(const float* __restrict__ P, Axis ai, Axis aj,
                                           const float* __restrict__ V, Axis ak,
                                           int r4, float* __restrict__ dst) {
  float fi = ai.f, fj = aj.f, fk = ak.f;
  float w00 = (1.f - fi) * (1.f - fj);
  float w01 = (1.f - fi) * fj;
  float w10 = fi * (1.f - fj);
  float w11 = fi * fj;
  float omk = 1.f - fk;
  float4 q00 = *(const float4*)(P + (ai.i0 * GG + aj.i0) * RR + r4);
  float4 q01 = *(const float4*)(P + (ai.i0 * GG + aj.i1) * RR + r4);
  float4 q10 = *(const float4*)(P + (ai.i1 * GG + aj.i0) * RR + r4);
  float4 q11 = *(const float4*)(P + (ai.i1 * GG + aj.i1) * RR + r4);
  float4 b0 = *(const float4*)(V + ak.i0 * RR + r4);
  float4 b1 = *(const float4*)(V + ak.i1 * RR + r4);
  float4 o;
  o.x = (w00 * q00.x + w01 * q01.x + w10 * q10.x + w11 * q11.x) * (omk * b0.x + fk * b1.x);
  o.y = (w00 * q00.y + w01 * q01.y + w10 * q10.y + w11 * q11.y) * (omk * b0.y + fk * b1.y);
  o.z = (w00 * q00.z + w01 * q01.z + w10 * q10.z + w11 * q11.z) * (omk * b0.z + fk * b1.z);
  o.w = (w00 * q00.w + w01 * q01.w + w10 * q10.w + w11 * q11.w) * (omk * b0.w + fk * b1.w);
  *(float4*)(dst + r4) = o;  // one ds_write_b128 (16B-aligned: dst,r4 mult of 4 words)
}

__global__ void __launch_bounds__(256, 4) tensorf_fused(
    const float4* __restrict__ sxyz, const int* __restrict__ sidx,
    const float* __restrict__ xyz,
    const float* __restrict__ Txy, const float* __restrict__ Txz, const float* __restrict__ Tyz,
    const float* __restrict__ Tx, const float* __restrict__ Ty, const float* __restrict__ Tz,
    const float* __restrict__ F, float* __restrict__ out, int n, int chunkLen) {
  __shared__ float featT[TP * FROW];  // 37.9 KB -> 4 blocks/CU
  __shared__ int oiS[TP];
  int b = blockIdx.x;
  int nb = (b & 7) * chunkLen + (b >> 3);  // XCD-aware: each XCD streams one Morton chunk
  int base = nb * TP;
  int tid = threadIdx.x;
  int g = tid >> 4;   // group 0..15, one point per group per iter
  int l = tid & 15;   // lane within group; lanes 0..11 do the loads

  // ---- phase 1: coalesced gather + interpolate -> featT[TP][144] ----
#pragma unroll 1
  for (int it = 0; it < TP / 16; ++it) {
    int pl = (it << 4) + g;
    int sp = base + pl;
    if (sp < n) {
      float x, y, z;
      int oi;
      if (sxyz) {
        float4 p4 = sxyz[sp];  // coalesced sorted records
        x = p4.x; y = p4.y; z = p4.z;
        oi = __float_as_int(p4.w);
      } else {
        oi = sidx[sp];
        x = xyz[oi * 3 + 0];
        y = xyz[oi * 3 + 1];
        z = xyz[oi * 3 + 2];
      }
      if (l == 12) oiS[pl] = oi;
      Axis ax = axis_interp(x), ay = axis_interp(y), az = axis_interp(z);
      if (l < 12) {
        int r4 = l << 2;
        float* dst = &featT[pl * FROW];
        gather_seg(Txy, ax, ay, Tz, az, r4, dst + 0 * RR);
        gather_seg(Txz, ax, az, Ty, ay, r4, dst + 1 * RR);
        gather_seg(Tyz, ay, az, Tx, ax, r4, dst + 2 * RR);
      }
    }
  }
  __syncthreads();

  // ---- phase 2: feat[144] @ F[144][27], 4 threads per point ----
  // q = wave index, FORCED uniform via readfirstlane so the F pointer lives in
  // SGPRs and all F reads are s_load broadcasts (round-2 regression: plain
  // tid>>6 made these 1008 per-lane global_load_dword + VGPR address math).
  int p = tid & (TP - 1);
  int q = __builtin_amdgcn_readfirstlane(tid >> 6);  // wave-uniform 0..3
  int cbase = (q == 3) ? 20 : q * 7;  // q3 overlaps q2 at c20 to stay in-bounds
  const float* Fh = F + cbase;
  const float* row = &featT[p * FROW];

  float acc[7];
#pragma unroll
  for (int c = 0; c < 7; ++c) acc[c] = 0.f;

#pragma unroll 4
  for (int k4 = 0; k4 < 36; ++k4) {
    float4 fv = *(const float4*)(row + 4 * k4);  // ds_read_b128
    const float* Fr = Fh + (k4 * 4) * CC;
#pragma unroll
    for (int c = 0; c < 7; ++c) {
      acc[c] = fmaf(fv.w, Fr[3 * CC + c],
               fmaf(fv.z, Fr[2 * CC + c],
               fmaf(fv.y, Fr[CC + c],
               fmaf(fv.x, Fr[c], acc[c]))));
    }
  }

  int sp = base + p;
  if (sp < n) {
    int oi = oiS[p];
    float* o = out + (size_t)oi * CC + cbase;
    if (q != 3) o[0] = acc[0];  // q3's c==0 (channel 20) is q2's copy
#pragma unroll
    for (int c = 1; c < 7; ++c) o[c] = acc[c];
  }
}

// ---------------- fallback (no workspace) ----------------
__global__ void __launch_bounds__(256) tensorf_naive(
    const float* __restrict__ xyz,
    const float* __restrict__ Pxy, const float* __restrict__ Pxz, const float* __restrict__ Pyz,
    const float* __restrict__ Vx, const float* __restrict__ Vy, const float* __restrict__ Vz,
    const float* __restrict__ F, float* __restrict__ out, int n) {
  int idx = blockIdx.x * blockDim.x + threadIdx.x;
  if (idx >= n) return;
  float x = xyz[idx * 3], y = xyz[idx * 3 + 1], z = xyz[idx * 3 + 2];
  Axis ax = axis_interp(x), ay = axis_interp(y), az = axis_interp(z);
  float acc[CC];
#pragma unroll
  for (int c = 0; c < CC; ++c) acc[c] = 0.f;
  const float* Ps[3] = {Pxy, Pxz, Pyz};
  const float* Vs[3] = {Vz, Vy, Vx};
  Axis A[3][2] = {{ax, ay}, {ax, az}, {ay, az}};
  Axis K[3] = {az, ay, ax};
#pragma unroll 1
  for (int s = 0; s < 3; ++s) {
    Axis ai = A[s][0], aj = A[s][1], ak = K[s];
    float fi = ai.f, fj = aj.f, fk = ak.f;
    float w00 = (1.f - fi) * (1.f - fj), w01 = (1.f - fi) * fj;
    float w10 = fi * (1.f - fj), w11 = fi * fj, omk = 1.f - fk;
#pragma unroll 1
    for (int r = 0; r < RR; ++r) {
      const float* pr = Ps[s] + r * HW2;
      float ft = (w00 * pr[ai.i0 * GG + aj.i0] + w01 * pr[ai.i0 * GG + aj.i1] +
                  w10 * pr[ai.i1 * GG + aj.i0] + w11 * pr[ai.i1 * GG + aj.i1]) *
                 (omk * Vs[s][r * GG + ak.i0] + fk * Vs[s][r * GG + ak.i1]);
      const float* Fr = F + (s * RR + r) * CC;
#pragma unroll
      for (int c = 0; c < CC; ++c) acc[c] = fmaf(ft, Fr[c], acc[c]);
    }
  }
  float* o = out + (size_t)idx * CC;
#pragma unroll
  for (int c = 0; c < CC; ++c) o[c] = acc[c];
}

extern "C" void kernel_launch(void* const* d_in, const int* in_sizes, int n_in,
                              void* d_out, int out_size, void* d_ws, size_t ws_size,
                              hipStream_t stream) {
  const float* xyz = (const float*)d_in[0];
  const float* pxy = (const float*)d_in[1];
  const float* pxz = (const float*)d_in[2];
  const float* pyz = (const float*)d_in[3];
  const float* vx = (const float*)d_in[4];
  const float* vy = (const float*)d_in[5];
  const float* vz = (const float*)d_in[6];
  const float* F = (const float*)d_in[7];
  float* out = (float*)d_out;
  int n = in_sizes[0] / 3;
  int nblk = (n + 255) / 256;

  size_t fixed = (size_t)(3 * NPLANE + 3 * NVEC) * sizeof(float) +
                 (size_t)NBUCK * sizeof(int);
  size_t need1 = fixed + (size_t)n * sizeof(int);      // sorted-index variant
  size_t need2 = fixed + (size_t)n * sizeof(float4);   // sorted-record variant

  if (ws_size >= need1) {
    float* w = (float*)d_ws;
    float* Txy = w;
    float* Txz = Txy + NPLANE;
    float* Tyz = Txz + NPLANE;
    float* Tx = Tyz + NPLANE;
    float* Ty = Tx + NVEC;
    float* Tz = Ty + NVEC;
    int* offs = (int*)(Tz + NVEC);

    int* sidx = nullptr;
    float4* sxyz = nullptr;
    if (ws_size >= need2) sxyz = (float4*)(offs + NBUCK);
    else sidx = (int*)(offs + NBUCK);

    hipMemsetAsync(offs, 0, (size_t)NBUCK * sizeof(int), stream);
    // proven chain: hist -> scan -> [scatter || transposes] -> fused
    hist_kernel<<<nblk, 256, 0, stream>>>(xyz, n, offs);
    scan_kernel<<<1, 1024, 0, stream>>>(offs);
    trans_scatter_kernel<<<nblk + TPB3 + VBLK, 256, 0, stream>>>(
        xyz, n, offs, sidx, sxyz, nblk,
        pxy, pxz, pyz, Txy, Txz, Tyz, vx, vy, vz, Tx, Ty, Tz);

    int ntile = (n + TP - 1) / TP;
    int chunkLen = (ntile + 7) / 8;
    tensorf_fused<<<chunkLen * 8, 256, 0, stream>>>(sxyz, sidx, xyz, Txy, Txz, Tyz,
                                                    Tx, Ty, Tz, F, out, n, chunkLen);
  } else {
    tensorf_naive<<<nblk, 256, 0, stream>>>(xyz, pxy, pxz, pyz, vx, vy, vz, F, out, n);
  }
}